// Round 1
// baseline (189.018 us; speedup 1.0000x reference)
//
#include <hip/hip_runtime.h>

#define BLOCK 256
#define LOG_2PI_F 1.8378770664093453f

// ws layout (float offsets):
//   0        : mus_sum  [2*D]   (atomic accum)
//   2D       : lsd_sum  [2*D]   (atomic accum)
//   4D+0..1  : logp_sum [2]     (atomic accum)
//   4D+2..3  : logdet_sum [2]
//   4D+4..5  : counts   [2]
//   4D+8     : mu_tab   [2*D]
//   6D+8     : a_tab    [2*D]   (= 0.5*exp(-2*lsd))
//   8D+8     : b_tab    [2*D]   (= -0.5*log(2pi) - lsd)

__global__ __launch_bounds__(BLOCK) void k_colsum(
    const float* __restrict__ mean,
    const float* __restrict__ log_sd,
    const int*   __restrict__ target,
    const float* __restrict__ logdet,
    float* __restrict__ ws,
    int N, int D, int rowsPerBlk)
{
    const int tid  = threadIdx.x;
    const int D4   = D >> 2;
    const int col  = blockIdx.x * (BLOCK * 4) + tid * 4;
    const int c4   = col >> 2;
    const int rowBase = blockIdx.y * rowsPerBlk;

    const float4* mean4 = reinterpret_cast<const float4*>(mean);
    const float4* lsd4  = reinterpret_cast<const float4*>(log_sd);

    float4 sM0 = make_float4(0.f,0.f,0.f,0.f);
    float4 sM1 = make_float4(0.f,0.f,0.f,0.f);
    float4 sL0 = make_float4(0.f,0.f,0.f,0.f);
    float4 sL1 = make_float4(0.f,0.f,0.f,0.f);

    #pragma unroll 4
    for (int r = 0; r < rowsPerBlk; ++r) {
        const int n = rowBase + r;
        // n is block-uniform -> target[n] wave-uniform; force scalar branch
        const int t = __builtin_amdgcn_readfirstlane(target[n]);
        const float4 m = mean4[(size_t)n * D4 + c4];
        const float4 l = lsd4 [(size_t)n * D4 + c4];
        if (t == 0) {
            sM0.x += m.x; sM0.y += m.y; sM0.z += m.z; sM0.w += m.w;
            sL0.x += l.x; sL0.y += l.y; sL0.z += l.z; sL0.w += l.w;
        } else {
            sM1.x += m.x; sM1.y += m.y; sM1.z += m.z; sM1.w += m.w;
            sL1.x += l.x; sL1.y += l.y; sL1.z += l.z; sL1.w += l.w;
        }
    }

    float* mus_sum = ws;
    float* lsd_sum = ws + 2 * D;
    atomicAdd(&mus_sum[col + 0], sM0.x);
    atomicAdd(&mus_sum[col + 1], sM0.y);
    atomicAdd(&mus_sum[col + 2], sM0.z);
    atomicAdd(&mus_sum[col + 3], sM0.w);
    atomicAdd(&mus_sum[D + col + 0], sM1.x);
    atomicAdd(&mus_sum[D + col + 1], sM1.y);
    atomicAdd(&mus_sum[D + col + 2], sM1.z);
    atomicAdd(&mus_sum[D + col + 3], sM1.w);
    atomicAdd(&lsd_sum[col + 0], sL0.x);
    atomicAdd(&lsd_sum[col + 1], sL0.y);
    atomicAdd(&lsd_sum[col + 2], sL0.z);
    atomicAdd(&lsd_sum[col + 3], sL0.w);
    atomicAdd(&lsd_sum[D + col + 0], sL1.x);
    atomicAdd(&lsd_sum[D + col + 1], sL1.y);
    atomicAdd(&lsd_sum[D + col + 2], sL1.z);
    atomicAdd(&lsd_sum[D + col + 3], sL1.w);

    // block (0,0) additionally computes counts + per-class logdet sums
    if (blockIdx.x == 0 && blockIdx.y == 0) {
        float ld0 = 0.f, ld1 = 0.f;
        int   c0  = 0;
        for (int n = tid; n < N; n += BLOCK) {
            const int t = target[n];
            const float v = logdet[n];
            if (t == 0) { c0++; ld0 += v; } else { ld1 += v; }
        }
        __shared__ float s0[BLOCK];
        __shared__ float s1[BLOCK];
        __shared__ int   sc[BLOCK];
        s0[tid] = ld0; s1[tid] = ld1; sc[tid] = c0;
        __syncthreads();
        for (int off = BLOCK / 2; off > 0; off >>= 1) {
            if (tid < off) {
                s0[tid] += s0[tid + off];
                s1[tid] += s1[tid + off];
                sc[tid] += sc[tid + off];
            }
            __syncthreads();
        }
        if (tid == 0) {
            float* stats = ws + 4 * D;
            stats[2] = s0[0];                 // logdet_sum[0]
            stats[3] = s1[0];                 // logdet_sum[1]
            stats[4] = (float)sc[0];          // counts[0]
            stats[5] = (float)(N - sc[0]);    // counts[1]
        }
    }
}

__global__ __launch_bounds__(BLOCK) void k_finalize1(
    float* __restrict__ ws, float* __restrict__ out, int D)
{
    const int idx = blockIdx.x * BLOCK + threadIdx.x;   // [0, 2*D)
    if (idx >= 2 * D) return;
    const float* mus_sum = ws;
    const float* lsd_sum = ws + 2 * D;
    const float* stats   = ws + 4 * D;
    const float cnt = (idx < D) ? stats[4] : stats[5];
    const float m = mus_sum[idx] / cnt;
    const float l = lsd_sum[idx] / cnt;
    out[1 + idx]         = m;   // mus
    out[1 + 2 * D + idx] = l;   // lsds
    float* mu_tab = ws + 4 * D + 8;
    float* a_tab  = mu_tab + 2 * D;
    float* b_tab  = a_tab  + 2 * D;
    mu_tab[idx] = m;
    a_tab[idx]  = 0.5f * expf(-2.f * l);
    b_tab[idx]  = -0.5f * LOG_2PI_F - l;
}

__global__ __launch_bounds__(BLOCK) void k_logp(
    const float* __restrict__ z,
    const int*   __restrict__ target,
    const float* __restrict__ ws,
    float* __restrict__ logp_out,
    float* __restrict__ logp_sum,
    int N, int D)
{
    const int wave = threadIdx.x >> 6;
    const int lane = threadIdx.x & 63;
    const int n    = blockIdx.x * 4 + wave;
    const int D4   = D >> 2;
    const bool active = (n < N);

    float acc = 0.f;
    int t = 0;
    if (active) {
        t = target[n];
        const float4* z4  = reinterpret_cast<const float4*>(z) + (size_t)n * D4;
        const float4* mu4 = reinterpret_cast<const float4*>(ws + 4 * D + 8) + (size_t)t * D4;
        const float4* a4  = mu4 + 2 * D4;   // a_tab is 2*D floats after mu_tab
        const float4* b4  = a4  + 2 * D4;
        for (int i = lane; i < D4; i += 64) {
            const float4 zz = z4[i];
            const float4 mu = mu4[i];
            const float4 aa = a4[i];
            const float4 bb = b4[i];
            float dx;
            dx = zz.x - mu.x; acc += bb.x - aa.x * dx * dx;
            dx = zz.y - mu.y; acc += bb.y - aa.y * dx * dx;
            dx = zz.z - mu.z; acc += bb.z - aa.z * dx * dx;
            dx = zz.w - mu.w; acc += bb.w - aa.w * dx * dx;
        }
    }
    #pragma unroll
    for (int m = 32; m >= 1; m >>= 1) acc += __shfl_xor(acc, m);

    __shared__ float s_acc[4];
    __shared__ int   s_t[4];
    if (lane == 0) {
        s_acc[wave] = active ? acc : 0.f;
        s_t[wave]   = t;
        if (active) logp_out[n] = acc;
    }
    __syncthreads();
    if (threadIdx.x == 0) {
        float c0 = 0.f, c1 = 0.f;
        #pragma unroll
        for (int w = 0; w < 4; ++w) {
            if (s_t[w] == 0) c0 += s_acc[w]; else c1 += s_acc[w];
        }
        atomicAdd(&logp_sum[0], c0);
        atomicAdd(&logp_sum[1], c1);
    }
}

__global__ void k_finalize2(const float* __restrict__ ws, float* __restrict__ out,
                            int D, int out_off)
{
    if (threadIdx.x == 0 && blockIdx.x == 0) {
        const float* stats = ws + 4 * D;
        const float lp0 = stats[0] / stats[4];
        const float lp1 = stats[1] / stats[5];
        const float ld0 = stats[2] / stats[4];
        const float ld1 = stats[3] / stats[5];
        out[out_off]     = lp0;            // log_p_total[0]
        out[out_off + 1] = lp1;            // log_p_total[1]
        out[0] = 0.5f * ((lp0 + ld0) + (lp1 + ld1));  // prior_logprob
    }
}

extern "C" void kernel_launch(void* const* d_in, const int* in_sizes, int n_in,
                              void* d_out, int out_size, void* d_ws, size_t ws_size,
                              hipStream_t stream)
{
    const float* z      = (const float*)d_in[0];
    const float* mean   = (const float*)d_in[1];
    const float* log_sd = (const float*)d_in[2];
    const float* logdet = (const float*)d_in[3];
    const int*   target = (const int*)d_in[4];
    float* out = (float*)d_out;
    float* ws  = (float*)d_ws;

    const int N = in_sizes[3];            // 8192
    const int D = in_sizes[0] / N;        // 3072

    // zero the atomic-accumulator + stats region (graph-capturable)
    hipMemsetAsync(d_ws, 0, (size_t)(4 * D + 8) * sizeof(float), stream);

    // pass 1: per-class column sums of mean/log_sd (+ counts, logdet sums)
    const int ROWS = 64;
    dim3 g1(D / (BLOCK * 4), N / ROWS);
    k_colsum<<<g1, BLOCK, 0, stream>>>(mean, log_sd, target, logdet, ws, N, D, ROWS);

    // finalize class params + precompute logp tables
    const int tot = 2 * D;
    k_finalize1<<<(tot + BLOCK - 1) / BLOCK, BLOCK, 0, stream>>>(ws, out, D);

    // pass 2: per-sample logp (one wave per row)
    k_logp<<<(N + 3) / 4, BLOCK, 0, stream>>>(z, target, ws,
                                              out + 1 + 4 * D,   // logp output
                                              ws + 4 * D,        // logp_sum
                                              N, D);

    // epilogue scalars
    k_finalize2<<<1, 64, 0, stream>>>(ws, out, D, 1 + 4 * D + N);
}

// Round 2
// 107.887 us; speedup vs baseline: 1.7520x; 1.7520x over previous
//
#include <hip/hip_runtime.h>

#define BLOCK 256
#define LOG_2PI_F 1.8378770664093453f
#define CS_ROWS 64      // rows per block in colsum
#define CS_RPW  16      // rows per wave (4 waves/block)

// ws layout (float offsets):
//   0        : mus_sum  [2*D]   (atomic accum)
//   2D       : lsd_sum  [2*D]   (atomic accum)
//   4D+0..7  : stats: [2] ld_sum0 [3] ld_sum1 [4] cnt0 [5] cnt1
//   4D+8     : p_tab   [2*D]   (= 0.5*exp(-2*lsd))
//   6D+8     : q_tab   [2*D]   (= 2*p*mu)
//   8D+8     : b_tab   [2*D]   (= -0.5*log2pi - lsd - p*mu^2)

__global__ __launch_bounds__(BLOCK) void k_colsum(
    const float* __restrict__ mean,
    const float* __restrict__ log_sd,
    const int*   __restrict__ target,
    const float* __restrict__ logdet,
    float* __restrict__ ws,
    int N, int D)
{
    const int wave = threadIdx.x >> 6;
    const int lane = threadIdx.x & 63;
    const int col  = blockIdx.x * 256 + lane * 4;   // 256 cols per block, all waves
    const int c4   = col >> 2;
    const int D4   = D >> 2;
    const int rowBase = blockIdx.y * CS_ROWS + wave * CS_RPW;
    const bool colOK = (col + 3 < D);

    const float4* mean4 = reinterpret_cast<const float4*>(mean);
    const float4* lsd4  = reinterpret_cast<const float4*>(log_sd);

    float4 sM0 = make_float4(0.f,0.f,0.f,0.f);
    float4 sM1 = make_float4(0.f,0.f,0.f,0.f);
    float4 sL0 = make_float4(0.f,0.f,0.f,0.f);
    float4 sL1 = make_float4(0.f,0.f,0.f,0.f);

    if (colOK) {
        #pragma unroll 4
        for (int r = 0; r < CS_RPW; ++r) {
            const int n = rowBase + r;
            if (n >= N) break;
            const int t = __builtin_amdgcn_readfirstlane(target[n]);
            const float4 m = mean4[(size_t)n * D4 + c4];
            const float4 l = lsd4 [(size_t)n * D4 + c4];
            if (t == 0) {
                sM0.x += m.x; sM0.y += m.y; sM0.z += m.z; sM0.w += m.w;
                sL0.x += l.x; sL0.y += l.y; sL0.z += l.z; sL0.w += l.w;
            } else {
                sM1.x += m.x; sM1.y += m.y; sM1.z += m.z; sM1.w += m.w;
                sL1.x += l.x; sL1.y += l.y; sL1.z += l.z; sL1.w += l.w;
            }
        }
    }

    // cross-wave LDS reduce (stride 17 -> 2-way bank alias, free)
    __shared__ float red[4][64][17];
    {
        float* rr = red[wave][lane];
        rr[0]=sM0.x; rr[1]=sM0.y; rr[2]=sM0.z; rr[3]=sM0.w;
        rr[4]=sM1.x; rr[5]=sM1.y; rr[6]=sM1.z; rr[7]=sM1.w;
        rr[8]=sL0.x; rr[9]=sL0.y; rr[10]=sL0.z; rr[11]=sL0.w;
        rr[12]=sL1.x; rr[13]=sL1.y; rr[14]=sL1.z; rr[15]=sL1.w;
    }
    __syncthreads();

    if (wave == 0 && colOK) {
        float v[16];
        #pragma unroll
        for (int j = 0; j < 16; ++j)
            v[j] = red[0][lane][j] + red[1][lane][j] + red[2][lane][j] + red[3][lane][j];
        float* mus_sum = ws;
        float* lsd_sum = ws + 2 * D;
        #pragma unroll
        for (int j = 0; j < 4; ++j) {
            atomicAdd(&mus_sum[col + j],     v[j]);
            atomicAdd(&mus_sum[D + col + j], v[4 + j]);
            atomicAdd(&lsd_sum[col + j],     v[8 + j]);
            atomicAdd(&lsd_sum[D + col + j], v[12 + j]);
        }
    }

    // block (0,0): counts + per-class logdet sums
    if (blockIdx.x == 0 && blockIdx.y == 0) {
        const int tid = threadIdx.x;
        float ld0 = 0.f, ld1 = 0.f;
        int   c0  = 0;
        for (int n = tid; n < N; n += BLOCK) {
            const int t = target[n];
            const float v = logdet[n];
            if (t == 0) { c0++; ld0 += v; } else { ld1 += v; }
        }
        __shared__ float s0[BLOCK];
        __shared__ float s1[BLOCK];
        __shared__ int   sc[BLOCK];
        s0[tid] = ld0; s1[tid] = ld1; sc[tid] = c0;
        __syncthreads();
        for (int off = BLOCK / 2; off > 0; off >>= 1) {
            if (tid < off) {
                s0[tid] += s0[tid + off];
                s1[tid] += s1[tid + off];
                sc[tid] += sc[tid + off];
            }
            __syncthreads();
        }
        if (tid == 0) {
            float* stats = ws + 4 * D;
            stats[2] = s0[0];
            stats[3] = s1[0];
            stats[4] = (float)sc[0];
            stats[5] = (float)(N - sc[0]);
        }
    }
}

__global__ __launch_bounds__(BLOCK) void k_finalize1(
    float* __restrict__ ws, float* __restrict__ out, int D)
{
    const int idx = blockIdx.x * BLOCK + threadIdx.x;   // [0, 2*D)
    if (idx >= 2 * D) return;
    const float* mus_sum = ws;
    const float* lsd_sum = ws + 2 * D;
    const float* stats   = ws + 4 * D;
    const float cnt = (idx < D) ? stats[4] : stats[5];
    const float m = mus_sum[idx] / cnt;
    const float l = lsd_sum[idx] / cnt;
    out[1 + idx]         = m;   // mus
    out[1 + 2 * D + idx] = l;   // lsds
    float* p_tab = ws + 4 * D + 8;
    float* q_tab = p_tab + 2 * D;
    float* b_tab = q_tab + 2 * D;
    const float p = 0.5f * expf(-2.f * l);
    p_tab[idx] = p;
    q_tab[idx] = 2.f * p * m;
    b_tab[idx] = -0.5f * LOG_2PI_F - l - p * m * m;
}

__global__ __launch_bounds__(BLOCK) void k_logp(
    const float* __restrict__ z,
    const int*   __restrict__ target,
    const float* __restrict__ ws,
    float* __restrict__ logp_out,
    int N, int D)
{
    const int wave = threadIdx.x >> 6;
    const int lane = threadIdx.x & 63;
    const int n    = blockIdx.x * 4 + wave;
    const int D4   = D >> 2;
    if (n >= N) return;

    const int t = __builtin_amdgcn_readfirstlane(target[n]);
    const float4* z4 = reinterpret_cast<const float4*>(z) + (size_t)n * D4;
    const float4* p4 = reinterpret_cast<const float4*>(ws + 4 * D + 8) + (size_t)t * D4;
    const float4* q4 = p4 + 2 * D4;
    const float4* b4 = q4 + 2 * D4;

    float acc = 0.f;
    #pragma unroll 4
    for (int i = lane; i < D4; i += 64) {
        const float4 zz = z4[i];
        const float4 pp = p4[i];
        const float4 qq = q4[i];
        const float4 bb = b4[i];
        float tx;
        tx = pp.x * zz.x; acc += bb.x + zz.x * (qq.x - tx);
        tx = pp.y * zz.y; acc += bb.y + zz.y * (qq.y - tx);
        tx = pp.z * zz.z; acc += bb.z + zz.z * (qq.z - tx);
        tx = pp.w * zz.w; acc += bb.w + zz.w * (qq.w - tx);
    }

    #pragma unroll
    for (int m = 32; m >= 1; m >>= 1) acc += __shfl_xor(acc, m);
    if (lane == 0) logp_out[n] = acc;
}

__global__ __launch_bounds__(1024) void k_finalize2(
    const float* __restrict__ logp,
    const int*   __restrict__ target,
    const float* __restrict__ ws,
    float* __restrict__ out,
    int N, int D, int out_off)
{
    const int tid = threadIdx.x;
    float c0 = 0.f, c1 = 0.f;
    for (int i = tid; i < N; i += 1024) {
        const float v = logp[i];
        if (target[i] == 0) c0 += v; else c1 += v;
    }
    __shared__ float s0[1024];
    __shared__ float s1[1024];
    s0[tid] = c0; s1[tid] = c1;
    __syncthreads();
    for (int off = 512; off > 0; off >>= 1) {
        if (tid < off) {
            s0[tid] += s0[tid + off];
            s1[tid] += s1[tid + off];
        }
        __syncthreads();
    }
    if (tid == 0) {
        const float* stats = ws + 4 * D;
        const float lp0 = s0[0] / stats[4];
        const float lp1 = s1[0] / stats[5];
        const float ld0 = stats[2] / stats[4];
        const float ld1 = stats[3] / stats[5];
        out[out_off]     = lp0;            // log_p_total[0]
        out[out_off + 1] = lp1;            // log_p_total[1]
        out[0] = 0.5f * ((lp0 + ld0) + (lp1 + ld1));  // prior_logprob
    }
}

extern "C" void kernel_launch(void* const* d_in, const int* in_sizes, int n_in,
                              void* d_out, int out_size, void* d_ws, size_t ws_size,
                              hipStream_t stream)
{
    const float* z      = (const float*)d_in[0];
    const float* mean   = (const float*)d_in[1];
    const float* log_sd = (const float*)d_in[2];
    const float* logdet = (const float*)d_in[3];
    const int*   target = (const int*)d_in[4];
    float* out = (float*)d_out;
    float* ws  = (float*)d_ws;

    const int N = in_sizes[3];            // 8192
    const int D = in_sizes[0] / N;        // 3072

    // zero the atomic-accumulator + stats region
    hipMemsetAsync(d_ws, 0, (size_t)(4 * D + 8) * sizeof(float), stream);

    // pass 1: per-class column sums (+ counts, logdet sums)
    dim3 g1((D + 255) / 256, (N + CS_ROWS - 1) / CS_ROWS);
    k_colsum<<<g1, BLOCK, 0, stream>>>(mean, log_sd, target, logdet, ws, N, D);

    // finalize class params + precompute logp tables
    const int tot = 2 * D;
    k_finalize1<<<(tot + BLOCK - 1) / BLOCK, BLOCK, 0, stream>>>(ws, out, D);

    // pass 2: per-sample logp (one wave per row), NO same-address atomics
    float* logp_out = out + 1 + 4 * D;
    k_logp<<<(N + 3) / 4, BLOCK, 0, stream>>>(z, target, ws, logp_out, N, D);

    // epilogue: class logp means + prior (single-block reduce, no atomics)
    k_finalize2<<<1, 1024, 0, stream>>>(logp_out, target, ws, out,
                                        N, D, 1 + 4 * D + N);
}